// Round 15
// baseline (185.026 us; speedup 1.0000x reference)
//
#include <hip/hip_runtime.h>
#include <hip/hip_bf16.h>
#include <stdint.h>

// NeighborhoodAttention1D: B=4, L=4096, C=512, H=16, hd=32, K=13
// cvt+pack (merged, one launch) ; GEMM1/GEMM2 (R8-verbatim structure,
// bounds(256,4): 4 blocks/CU) ; natt

typedef __attribute__((ext_vector_type(8))) short short8;   // 8 x bf16 frag
typedef __attribute__((ext_vector_type(4))) float f32x4;    // MFMA C/D frag
typedef __attribute__((ext_vector_type(8))) unsigned short u16x8;
typedef __attribute__((ext_vector_type(4))) float float4v;

#define NB 4
#define NL 4096
#define NC 512
#define NH 16
#define HD 32
#define KW 13
#define KHALF 6
#define NM (NB*NL)   // 16384 rows

__device__ __forceinline__ float b2f(unsigned short u) {
  union { unsigned int i; float f; } x; x.i = ((unsigned int)u) << 16; return x.f;
}
__device__ __forceinline__ unsigned short f2b(float f) {
  __hip_bfloat16 h = __float2bfloat16(f);   // RNE
  return __builtin_bit_cast(unsigned short, h);
}
__device__ __forceinline__ void gll16(const void* g, unsigned short* l) {
  __builtin_amdgcn_global_load_lds(
      (const __attribute__((address_space(1))) void*)g,
      (__attribute__((address_space(3))) void*)l, 16, 0, 0);
}

// ---- merged: x->bf16 convert (blocks 0..4095) + W frag-pack (4096..4607) ---
// R8 pack grouping: g = ((((tn*8+kt)*2+wn)*4+nj)*2+kb)*64 + lane
//   n = tn*128 + wn*64 + nj*16 + (lane&15), k = kt*64 + (kb*4+(lane>>4))*8 + e
__device__ __forceinline__ void pack_one(const float* __restrict__ W,
                                         unsigned short* __restrict__ Bf,
                                         int N, int g) {
  int lane = g & 63;
  int kb   = (g >> 6) & 1;
  int nj   = (g >> 7) & 3;
  int wn   = (g >> 9) & 1;
  int kt   = (g >> 10) & 7;
  int tn   = g >> 13;
  int n  = tn * 128 + wn * 64 + nj * 16 + (lane & 15);
  int k0 = kt * 64 + (kb * 4 + (lane >> 4)) * 8;
  u16x8 u;
  #pragma unroll
  for (int e = 0; e < 8; ++e) u[e] = f2b(W[(long)(k0 + e) * N + n]);
  ((u16x8*)Bf)[g] = u;
}
__global__ __launch_bounds__(256)
void cvt_and_pack(const float* __restrict__ x, unsigned short* __restrict__ xb,
                  const float* __restrict__ W1, unsigned short* __restrict__ Bf1,
                  const float* __restrict__ W2, unsigned short* __restrict__ Bf2) {
  int bid = blockIdx.x;
  if (bid < 4096) {                      // x -> bf16, 8 elems/thread
    long i = (long)bid * 256 + threadIdx.x;
    const float4v* in4 = (const float4v*)x;
    float4v a = in4[i * 2];
    float4v b = in4[i * 2 + 1];
    u16x8 u;
    u[0] = f2b(a.x); u[1] = f2b(a.y); u[2] = f2b(a.z); u[3] = f2b(a.w);
    u[4] = f2b(b.x); u[5] = f2b(b.y); u[6] = f2b(b.z); u[7] = f2b(b.w);
    ((u16x8*)xb)[i] = u;
  } else {                               // weight packing (131072 groups)
    int g = (bid - 4096) * 256 + threadIdx.x;
    if (g < 98304) pack_one(W1, Bf1, 1536, g);
    else           pack_one(W2, Bf2, 512, g - 98304);
  }
}

#define BAR() __builtin_amdgcn_s_barrier()
#define LGK0() do { asm volatile("s_waitcnt lgkmcnt(0)" ::: "memory"); \
                    __builtin_amdgcn_sched_barrier(0); } while (0)
#define VM(N) asm volatile("s_waitcnt vmcnt(" #N ")" ::: "memory")

// ====== R8-verbatim 128x128 GEMM: A-only LDS (32KB dbuf), B frag-direct ====
// C[M,N] = A[M,K]*W + bias, W frag-packed. K=512 -> 8 K-tiles of 64.
// 256 threads = 4 waves (2M x 2N), per-wave 64x64 out = acc[4][4].
// Regs: acc 64 + af 16 + bf 16 + addr ~= 110; measured VGPR_Count=128 under
// bounds(256,3) -> bounds(256,4) budget is exactly 128: same codegen, but
// residency cap 3->4 blocks/CU (LDS allows 5). TRIPWIRE: if VGPR>128 were
// needed the compiler would spill (R9/R12) or split ranges (R13) -- watch
// VGPR_Count==128 and WRITE_SIZE==49152.
// Per iter kt (buf kt&1): LDBG(kt) | LDA | lgkm0 | BAR | stage A(kt+2) |
//   VM(4) | MFMA | BAR.
// vmcnt ledger (prologue A(0)4,A(1)4; tile kt issues B(kt)8, A(kt+2)4):
//   prologue VM(4) -> A(0) landed. tile kt (0..5): outstanding
//   {A(kt+1)4, B(kt)8, A(kt+2)4}=16 -> VM(4) retires A(kt+1)+B(kt);
//   end-BAR publishes A(kt+1). kt=6: {A(7)4,B(6)8} VM(0). kt=7: {B(7)8} VM(0).
// Swizzle: chunk ^= (row&7), both-sides (R2..R8-verified: 0 bank conflicts).

__device__ __forceinline__ void stage_tileA(const unsigned short* __restrict__ G,
                                            long rowBase, int K, int kt,
                                            unsigned short* ldsDst, int tid) {
  int r  = tid >> 3;                       // 0..31
  int ch = (tid & 7) ^ (r & 7);            // inverse-swizzled source chunk
  const unsigned short* s0 = G + (rowBase + r) * (long)K + kt * 64 + ch * 8;
  unsigned short* d0 = ldsDst + tid * 8;
  #pragma unroll
  for (int q = 0; q < 4; ++q)              // rows r, r+32, r+64, r+96
    gll16(s0 + (long)32 * q * K, d0 + 2048 * q);
}

// af[ii][kb] <- A row wm*64 + ii*16 + lr, 16B chunk (kb*4+lk)^(row&7)
#define LDA_B16(ABASE) do { \
  const char* _ba = (const char*)(ABASE); \
  _Pragma("unroll") for (int ii = 0; ii < 4; ++ii) { \
    int _row = wm*64 + ii*16 + lr; \
    _Pragma("unroll") for (int kb = 0; kb < 2; ++kb) \
      af[ii][kb] = *(const short8*)(_ba + _row*128 + (((kb*4+lk) ^ lr7) * 16)); \
  } \
} while (0)

// bf[nj][kb] <- packed B frags for K-tile KT (8 coalesced 16B loads, L2-hot)
#define LDBG(KT) do { \
  const short8* _bp = (const short8*)(Bfw + (long)(KT) * 8192) + lane; \
  _Pragma("unroll") for (int nj = 0; nj < 4; ++nj) \
    _Pragma("unroll") for (int kb = 0; kb < 2; ++kb) \
      bf[nj][kb] = _bp[(nj*2 + kb) * 64]; \
} while (0)

#define MMA_ALL() do { \
  __builtin_amdgcn_s_setprio(1); \
  _Pragma("unroll") for (int ii = 0; ii < 4; ++ii) \
    _Pragma("unroll") for (int jj = 0; jj < 4; ++jj) \
      _Pragma("unroll") for (int kb = 0; kb < 2; ++kb) \
        acc[ii][jj] = __builtin_amdgcn_mfma_f32_16x16x32_bf16( \
            af[ii][kb], bf[jj][kb], acc[ii][jj], 0, 0, 0); \
  __builtin_amdgcn_s_setprio(0); \
} while (0)

#define GTILE(ABUF, KT, STG, VMARG) do { \
  LDBG(KT); \
  LDA_B16(ABUF); \
  LGK0(); \
  BAR(); \
  if (STG) stage_tileA(Ag, mBase, K, (KT) + 2, ABUF, tid); \
  VMARG; \
  MMA_ALL(); \
  BAR(); \
} while (0)

template<int OUT_BF16>
__global__ __launch_bounds__(256, 4)
void gemm128(const unsigned short* __restrict__ Ag,
             const unsigned short* __restrict__ Bf,
             const float* __restrict__ bias,
             void* __restrict__ Cout,
             int M, int N, int K, int tilesN) {
  __shared__ __align__(16) unsigned short lds[16384];   // 32 KiB (A dbuf)

  int tid = threadIdx.x;
  int nwg = gridDim.x;                   // 1536 / 512, both %8==0
  int cpx = nwg >> 3;
  int wg  = ((int)blockIdx.x & 7) * cpx + ((int)blockIdx.x >> 3);  // XCD swizzle
  int tm = wg / tilesN, tn = wg % tilesN;
  long mBase = (long)tm * 128;
  long nBase = (long)tn * 128;

  int lane = tid & 63, wave = tid >> 6;
  int wm = wave >> 1, wn = wave & 1;
  int lr = lane & 15, lk = lane >> 4, lr7 = lr & 7;

  const unsigned short* Bfw = Bf + (long)tn * 65536 + wn * 4096;

  unsigned short* A0 = lds;              // buf0 A (128x64 bf16)
  unsigned short* A1 = lds + 8192;       // buf1 A

  f32x4 acc[4][4];
  #pragma unroll
  for (int i = 0; i < 4; ++i)
    #pragma unroll
    for (int j = 0; j < 4; ++j) acc[i][j] = (f32x4){0.f, 0.f, 0.f, 0.f};

  short8 af[4][2], bf[4][2];

  // ---- prologue: A(0)->buf0, A(1)->buf1 (8 gll16/thread) ----
  stage_tileA(Ag, mBase, K, 0, A0, tid);
  stage_tileA(Ag, mBase, K, 1, A1, tid);
  VM(4);                       // A(0) landed (A(1)'s 4 in flight)
  BAR();

  #pragma unroll 1
  for (int i = 0; i < 3; ++i) {
    GTILE(A0, 2*i,     true, VM(4));
    GTILE(A1, 2*i + 1, true, VM(4));
  }
  GTILE(A0, 6, false, VM(0));
  GTILE(A1, 7, false, VM(0));

  // ---- epilogue: C/D layout col = lane&15, row = (lane>>4)*4 + r --------
  long rowb = mBase + wm * 64 + (lane >> 4) * 4;
  int  colb = (int)nBase + wn * 64 + lr;
  if (OUT_BF16) {
    unsigned short* C = (unsigned short*)Cout;
    #pragma unroll
    for (int mi = 0; mi < 4; ++mi)
      #pragma unroll
      for (int nj = 0; nj < 4; ++nj) {
        int col = colb + nj * 16;
        float bv = bias[col];
        #pragma unroll
        for (int r = 0; r < 4; ++r)
          C[(rowb + mi * 16 + r) * (long)N + col] = f2b(acc[mi][nj][r] + bv);
      }
  } else {
    float* C = (float*)Cout;
    #pragma unroll
    for (int mi = 0; mi < 4; ++mi)
      #pragma unroll
      for (int nj = 0; nj < 4; ++nj) {
        int col = colb + nj * 16;
        float bv = bias[col];
        #pragma unroll
        for (int r = 0; r < 4; ++r)
          C[(rowb + mi * 16 + r) * (long)N + col] = acc[mi][nj][r] + bv;
      }
  }
}

// ---------------- neighborhood attention: 1 thread per (b,l,h) ------------
__global__ __launch_bounds__(256)
void natt(const unsigned short* __restrict__ qkv, const float* __restrict__ rpb,
          unsigned short* __restrict__ out) {
  int tid = blockIdx.x * 256 + threadIdx.x;
  int h = tid & 15;
  int l = (tid >> 4) & (NL - 1);
  int b = tid >> 16;
  const float scale = 0.17677669529663687f;

  long qb = ((long)(b * NL + l) * 3) * NC + h * HD;
  float q[HD];
  {
    const u16x8* q8 = (const u16x8*)(qkv + qb);
    #pragma unroll
    for (int w = 0; w < 4; ++w) {
      u16x8 u = q8[w];
      #pragma unroll
      for (int e = 0; e < 8; ++e) q[w * 8 + e] = b2f(u[e]) * scale;
    }
  }

  int ni = l - KHALF;
  if (ni < 0) ni = 0;
  if (ni > NL - KW) ni = NL - KW;
  const float* rb = rpb + h * (2 * KW - 1) + (ni - l + KW - 1);

  float p[KW];
  float mx = -1e30f;
  #pragma unroll
  for (int j = 0; j < KW; ++j) {
    long kb = ((long)(b * NL + ni + j) * 3 + 1) * NC + h * HD;
    const u16x8* k8 = (const u16x8*)(qkv + kb);
    float s = 0.f;
    #pragma unroll
    for (int w = 0; w < 4; ++w) {
      u16x8 u = k8[w];
      #pragma unroll
      for (int e = 0; e < 8; ++e) s += q[w * 8 + e] * b2f(u[e]);
    }
    s += rb[j];
    p[j] = s;
    mx = fmaxf(mx, s);
  }

  float sum = 0.f;
  #pragma unroll
  for (int j = 0; j < KW; ++j) { p[j] = __expf(p[j] - mx); sum += p[j]; }
  float inv = 1.0f / sum;

  float o[HD];
  #pragma unroll
  for (int d = 0; d < HD; ++d) o[d] = 0.f;
  #pragma unroll
  for (int j = 0; j < KW; ++j) {
    long vb = ((long)(b * NL + ni + j) * 3 + 2) * NC + h * HD;
    const u16x8* v8 = (const u16x8*)(qkv + vb);
    float wj = p[j] * inv;
    #pragma unroll
    for (int w = 0; w < 4; ++w) {
      u16x8 u = v8[w];
      #pragma unroll
      for (int e = 0; e < 8; ++e) o[w * 8 + e] += wj * b2f(u[e]);
    }
  }

  unsigned short* op = out + (long)(b * NL + l) * NC + h * HD;
  #pragma unroll
  for (int w = 0; w < 4; ++w) {
    u16x8 u;
    #pragma unroll
    for (int e = 0; e < 8; ++e) u[e] = f2b(o[w * 8 + e]);
    *((u16x8*)(op + w * 8)) = u;
  }
}

// ---------------------------------------------------------------------------
extern "C" void kernel_launch(void* const* d_in, const int* in_sizes, int n_in,
                              void* d_out, int out_size, void* d_ws, size_t ws_size,
                              hipStream_t stream) {
  const float* x      = (const float*)d_in[0];
  const float* qkv_w  = (const float*)d_in[1];
  const float* qkv_b  = (const float*)d_in[2];
  const float* rpb    = (const float*)d_in[3];
  const float* proj_w = (const float*)d_in[4];
  const float* proj_b = (const float*)d_in[5];
  float* out = (float*)d_out;

  char* ws = (char*)d_ws;
  unsigned short* xb   = (unsigned short*)(ws);              // 16,777,216 B
  unsigned short* Bf1  = (unsigned short*)(ws + 16777216);   //  1,572,864 B
  unsigned short* Bf2  = (unsigned short*)(ws + 18350080);   //    524,288 B
  unsigned short* qkvo = (unsigned short*)(ws + 18874368);   // 50,331,648 B
  unsigned short* attno= (unsigned short*)(ws + 69206016);   // 16,777,216 B

  cvt_and_pack<<<dim3(4608), dim3(256), 0, stream>>>(x, xb, qkv_w, Bf1,
                                                     proj_w, Bf2);
  // qkv = x @ qkv_w + b   (bf16 out): 1536 blocks
  gemm128<1><<<dim3(1536), dim3(256), 0, stream>>>(xb, Bf1, qkv_b, qkvo,
                                                   NM, 1536, 512, 12);
  natt<<<dim3(1024), dim3(256), 0, stream>>>(qkvo, rpb, attno);
  // out = attn @ proj_w + b  (fp32 out): 512 blocks
  gemm128<0><<<dim3(512), dim3(256), 0, stream>>>(attno, Bf2, proj_b, out,
                                                  NM, 512, 512, 4);
}

// Round 16
// 95.276 us; speedup vs baseline: 1.9420x; 1.9420x over previous
//
#include <hip/hip_runtime.h>
#include <hip/hip_bf16.h>
#include <stdint.h>

// NeighborhoodAttention1D: B=4, L=4096, C=512, H=16, hd=32, K=13
// cvt+pack (merged, one launch) ; GEMM1/GEMM2 (R8-verbatim: A-LDS dbuf gll16,
// 2Mx2N waves, B frag-direct to regs, bounds(256,3)) ; natt
// == R14 configuration (banked best: 93.6us). R15's bounds(256,4) snapped the
// allocator to the 64-VGPR class and spilled (WRITE 317MB, 185us) — (256,3)
// is the ONLY stable operating point (R9/R11/R13/R15 = 4 failure modes).

typedef __attribute__((ext_vector_type(8))) short short8;   // 8 x bf16 frag
typedef __attribute__((ext_vector_type(4))) float f32x4;    // MFMA C/D frag
typedef __attribute__((ext_vector_type(8))) unsigned short u16x8;
typedef __attribute__((ext_vector_type(4))) float float4v;

#define NB 4
#define NL 4096
#define NC 512
#define NH 16
#define HD 32
#define KW 13
#define KHALF 6
#define NM (NB*NL)   // 16384 rows

__device__ __forceinline__ float b2f(unsigned short u) {
  union { unsigned int i; float f; } x; x.i = ((unsigned int)u) << 16; return x.f;
}
__device__ __forceinline__ unsigned short f2b(float f) {
  __hip_bfloat16 h = __float2bfloat16(f);   // RNE
  return __builtin_bit_cast(unsigned short, h);
}
__device__ __forceinline__ void gll16(const void* g, unsigned short* l) {
  __builtin_amdgcn_global_load_lds(
      (const __attribute__((address_space(1))) void*)g,
      (__attribute__((address_space(3))) void*)l, 16, 0, 0);
}

// ---- merged: x->bf16 convert (blocks 0..4095) + W frag-pack (4096..4607) ---
// R8 pack grouping: g = ((((tn*8+kt)*2+wn)*4+nj)*2+kb)*64 + lane
//   n = tn*128 + wn*64 + nj*16 + (lane&15), k = kt*64 + (kb*4+(lane>>4))*8 + e
__device__ __forceinline__ void pack_one(const float* __restrict__ W,
                                         unsigned short* __restrict__ Bf,
                                         int N, int g) {
  int lane = g & 63;
  int kb   = (g >> 6) & 1;
  int nj   = (g >> 7) & 3;
  int wn   = (g >> 9) & 1;
  int kt   = (g >> 10) & 7;
  int tn   = g >> 13;
  int n  = tn * 128 + wn * 64 + nj * 16 + (lane & 15);
  int k0 = kt * 64 + (kb * 4 + (lane >> 4)) * 8;
  u16x8 u;
  #pragma unroll
  for (int e = 0; e < 8; ++e) u[e] = f2b(W[(long)(k0 + e) * N + n]);
  ((u16x8*)Bf)[g] = u;
}
__global__ __launch_bounds__(256)
void cvt_and_pack(const float* __restrict__ x, unsigned short* __restrict__ xb,
                  const float* __restrict__ W1, unsigned short* __restrict__ Bf1,
                  const float* __restrict__ W2, unsigned short* __restrict__ Bf2) {
  int bid = blockIdx.x;
  if (bid < 4096) {                      // x -> bf16, 8 elems/thread
    long i = (long)bid * 256 + threadIdx.x;
    const float4v* in4 = (const float4v*)x;
    float4v a = in4[i * 2];
    float4v b = in4[i * 2 + 1];
    u16x8 u;
    u[0] = f2b(a.x); u[1] = f2b(a.y); u[2] = f2b(a.z); u[3] = f2b(a.w);
    u[4] = f2b(b.x); u[5] = f2b(b.y); u[6] = f2b(b.z); u[7] = f2b(b.w);
    ((u16x8*)xb)[i] = u;
  } else {                               // weight packing (131072 groups)
    int g = (bid - 4096) * 256 + threadIdx.x;
    if (g < 98304) pack_one(W1, Bf1, 1536, g);
    else           pack_one(W2, Bf2, 512, g - 98304);
  }
}

#define BAR() __builtin_amdgcn_s_barrier()
#define LGK0() do { asm volatile("s_waitcnt lgkmcnt(0)" ::: "memory"); \
                    __builtin_amdgcn_sched_barrier(0); } while (0)
#define VM(N) asm volatile("s_waitcnt vmcnt(" #N ")" ::: "memory")

// ====== R8-verbatim 128x128 GEMM: A-only LDS (32KB dbuf), B frag-direct ====
// C[M,N] = A[M,K]*W + bias, W frag-packed. K=512 -> 8 K-tiles of 64.
// 256 threads = 4 waves (2M x 2N), per-wave 64x64 out = acc[4][4].
// Regs: acc 64 + af 16 + bf 16 + addr ~= 110 -> VGPR 128 stable at (256,3).
// Per iter kt (buf kt&1): LDBG(kt) | LDA | lgkm0 | BAR | stage A(kt+2) |
//   VM(4) | MFMA | BAR.
// vmcnt ledger (prologue A(0)4,A(1)4; tile kt issues B(kt)8, A(kt+2)4):
//   prologue VM(4) -> A(0) landed. tile kt (0..5): outstanding
//   {A(kt+1)4, B(kt)8, A(kt+2)4}=16 -> VM(4) retires A(kt+1)+B(kt);
//   end-BAR publishes A(kt+1). kt=6: {A(7)4,B(6)8} VM(0). kt=7: {B(7)8} VM(0).
// Swizzle: chunk ^= (row&7), both-sides (R2..R8-verified: 0 bank conflicts).

__device__ __forceinline__ void stage_tileA(const unsigned short* __restrict__ G,
                                            long rowBase, int K, int kt,
                                            unsigned short* ldsDst, int tid) {
  int r  = tid >> 3;                       // 0..31
  int ch = (tid & 7) ^ (r & 7);            // inverse-swizzled source chunk
  const unsigned short* s0 = G + (rowBase + r) * (long)K + kt * 64 + ch * 8;
  unsigned short* d0 = ldsDst + tid * 8;
  #pragma unroll
  for (int q = 0; q < 4; ++q)              // rows r, r+32, r+64, r+96
    gll16(s0 + (long)32 * q * K, d0 + 2048 * q);
}

// af[ii][kb] <- A row wm*64 + ii*16 + lr, 16B chunk (kb*4+lk)^(row&7)
#define LDA_B16(ABASE) do { \
  const char* _ba = (const char*)(ABASE); \
  _Pragma("unroll") for (int ii = 0; ii < 4; ++ii) { \
    int _row = wm*64 + ii*16 + lr; \
    _Pragma("unroll") for (int kb = 0; kb < 2; ++kb) \
      af[ii][kb] = *(const short8*)(_ba + _row*128 + (((kb*4+lk) ^ lr7) * 16)); \
  } \
} while (0)

// bf[nj][kb] <- packed B frags for K-tile KT (8 coalesced 16B loads, L2-hot)
#define LDBG(KT) do { \
  const short8* _bp = (const short8*)(Bfw + (long)(KT) * 8192) + lane; \
  _Pragma("unroll") for (int nj = 0; nj < 4; ++nj) \
    _Pragma("unroll") for (int kb = 0; kb < 2; ++kb) \
      bf[nj][kb] = _bp[(nj*2 + kb) * 64]; \
} while (0)

#define MMA_ALL() do { \
  __builtin_amdgcn_s_setprio(1); \
  _Pragma("unroll") for (int ii = 0; ii < 4; ++ii) \
    _Pragma("unroll") for (int jj = 0; jj < 4; ++jj) \
      _Pragma("unroll") for (int kb = 0; kb < 2; ++kb) \
        acc[ii][jj] = __builtin_amdgcn_mfma_f32_16x16x32_bf16( \
            af[ii][kb], bf[jj][kb], acc[ii][jj], 0, 0, 0); \
  __builtin_amdgcn_s_setprio(0); \
} while (0)

#define GTILE(ABUF, KT, STG, VMARG) do { \
  LDBG(KT); \
  LDA_B16(ABUF); \
  LGK0(); \
  BAR(); \
  if (STG) stage_tileA(Ag, mBase, K, (KT) + 2, ABUF, tid); \
  VMARG; \
  MMA_ALL(); \
  BAR(); \
} while (0)

template<int OUT_BF16>
__global__ __launch_bounds__(256, 3)
void gemm128(const unsigned short* __restrict__ Ag,
             const unsigned short* __restrict__ Bf,
             const float* __restrict__ bias,
             void* __restrict__ Cout,
             int M, int N, int K, int tilesN) {
  __shared__ __align__(16) unsigned short lds[16384];   // 32 KiB (A dbuf)

  int tid = threadIdx.x;
  int nwg = gridDim.x;                   // 1536 / 512, both %8==0
  int cpx = nwg >> 3;
  int wg  = ((int)blockIdx.x & 7) * cpx + ((int)blockIdx.x >> 3);  // XCD swizzle
  int tm = wg / tilesN, tn = wg % tilesN;
  long mBase = (long)tm * 128;
  long nBase = (long)tn * 128;

  int lane = tid & 63, wave = tid >> 6;
  int wm = wave >> 1, wn = wave & 1;
  int lr = lane & 15, lk = lane >> 4, lr7 = lr & 7;

  const unsigned short* Bfw = Bf + (long)tn * 65536 + wn * 4096;

  unsigned short* A0 = lds;              // buf0 A (128x64 bf16)
  unsigned short* A1 = lds + 8192;       // buf1 A

  f32x4 acc[4][4];
  #pragma unroll
  for (int i = 0; i < 4; ++i)
    #pragma unroll
    for (int j = 0; j < 4; ++j) acc[i][j] = (f32x4){0.f, 0.f, 0.f, 0.f};

  short8 af[4][2], bf[4][2];

  // ---- prologue: A(0)->buf0, A(1)->buf1 (8 gll16/thread) ----
  stage_tileA(Ag, mBase, K, 0, A0, tid);
  stage_tileA(Ag, mBase, K, 1, A1, tid);
  VM(4);                       // A(0) landed (A(1)'s 4 in flight)
  BAR();

  #pragma unroll 1
  for (int i = 0; i < 3; ++i) {
    GTILE(A0, 2*i,     true, VM(4));
    GTILE(A1, 2*i + 1, true, VM(4));
  }
  GTILE(A0, 6, false, VM(0));
  GTILE(A1, 7, false, VM(0));

  // ---- epilogue: C/D layout col = lane&15, row = (lane>>4)*4 + r --------
  long rowb = mBase + wm * 64 + (lane >> 4) * 4;
  int  colb = (int)nBase + wn * 64 + lr;
  if (OUT_BF16) {
    unsigned short* C = (unsigned short*)Cout;
    #pragma unroll
    for (int mi = 0; mi < 4; ++mi)
      #pragma unroll
      for (int nj = 0; nj < 4; ++nj) {
        int col = colb + nj * 16;
        float bv = bias[col];
        #pragma unroll
        for (int r = 0; r < 4; ++r)
          C[(rowb + mi * 16 + r) * (long)N + col] = f2b(acc[mi][nj][r] + bv);
      }
  } else {
    float* C = (float*)Cout;
    #pragma unroll
    for (int mi = 0; mi < 4; ++mi)
      #pragma unroll
      for (int nj = 0; nj < 4; ++nj) {
        int col = colb + nj * 16;
        float bv = bias[col];
        #pragma unroll
        for (int r = 0; r < 4; ++r)
          C[(rowb + mi * 16 + r) * (long)N + col] = acc[mi][nj][r] + bv;
      }
  }
}

// ---------------- neighborhood attention: 1 thread per (b,l,h) ------------
__global__ __launch_bounds__(256)
void natt(const unsigned short* __restrict__ qkv, const float* __restrict__ rpb,
          unsigned short* __restrict__ out) {
  int tid = blockIdx.x * 256 + threadIdx.x;
  int h = tid & 15;
  int l = (tid >> 4) & (NL - 1);
  int b = tid >> 16;
  const float scale = 0.17677669529663687f;

  long qb = ((long)(b * NL + l) * 3) * NC + h * HD;
  float q[HD];
  {
    const u16x8* q8 = (const u16x8*)(qkv + qb);
    #pragma unroll
    for (int w = 0; w < 4; ++w) {
      u16x8 u = q8[w];
      #pragma unroll
      for (int e = 0; e < 8; ++e) q[w * 8 + e] = b2f(u[e]) * scale;
    }
  }

  int ni = l - KHALF;
  if (ni < 0) ni = 0;
  if (ni > NL - KW) ni = NL - KW;
  const float* rb = rpb + h * (2 * KW - 1) + (ni - l + KW - 1);

  float p[KW];
  float mx = -1e30f;
  #pragma unroll
  for (int j = 0; j < KW; ++j) {
    long kb = ((long)(b * NL + ni + j) * 3 + 1) * NC + h * HD;
    const u16x8* k8 = (const u16x8*)(qkv + kb);
    float s = 0.f;
    #pragma unroll
    for (int w = 0; w < 4; ++w) {
      u16x8 u = k8[w];
      #pragma unroll
      for (int e = 0; e < 8; ++e) s += q[w * 8 + e] * b2f(u[e]);
    }
    s += rb[j];
    p[j] = s;
    mx = fmaxf(mx, s);
  }

  float sum = 0.f;
  #pragma unroll
  for (int j = 0; j < KW; ++j) { p[j] = __expf(p[j] - mx); sum += p[j]; }
  float inv = 1.0f / sum;

  float o[HD];
  #pragma unroll
  for (int d = 0; d < HD; ++d) o[d] = 0.f;
  #pragma unroll
  for (int j = 0; j < KW; ++j) {
    long vb = ((long)(b * NL + ni + j) * 3 + 2) * NC + h * HD;
    const u16x8* v8 = (const u16x8*)(qkv + vb);
    float wj = p[j] * inv;
    #pragma unroll
    for (int w = 0; w < 4; ++w) {
      u16x8 u = v8[w];
      #pragma unroll
      for (int e = 0; e < 8; ++e) o[w * 8 + e] += wj * b2f(u[e]);
    }
  }

  unsigned short* op = out + (long)(b * NL + l) * NC + h * HD;
  #pragma unroll
  for (int w = 0; w < 4; ++w) {
    u16x8 u;
    #pragma unroll
    for (int e = 0; e < 8; ++e) u[e] = f2b(o[w * 8 + e]);
    *((u16x8*)(op + w * 8)) = u;
  }
}

// ---------------------------------------------------------------------------
extern "C" void kernel_launch(void* const* d_in, const int* in_sizes, int n_in,
                              void* d_out, int out_size, void* d_ws, size_t ws_size,
                              hipStream_t stream) {
  const float* x      = (const float*)d_in[0];
  const float* qkv_w  = (const float*)d_in[1];
  const float* qkv_b  = (const float*)d_in[2];
  const float* rpb    = (const float*)d_in[3];
  const float* proj_w = (const float*)d_in[4];
  const float* proj_b = (const float*)d_in[5];
  float* out = (float*)d_out;

  char* ws = (char*)d_ws;
  unsigned short* xb   = (unsigned short*)(ws);              // 16,777,216 B
  unsigned short* Bf1  = (unsigned short*)(ws + 16777216);   //  1,572,864 B
  unsigned short* Bf2  = (unsigned short*)(ws + 18350080);   //    524,288 B
  unsigned short* qkvo = (unsigned short*)(ws + 18874368);   // 50,331,648 B
  unsigned short* attno= (unsigned short*)(ws + 69206016);   // 16,777,216 B

  cvt_and_pack<<<dim3(4608), dim3(256), 0, stream>>>(x, xb, qkv_w, Bf1,
                                                     proj_w, Bf2);
  // qkv = x @ qkv_w + b   (bf16 out): 1536 blocks
  gemm128<1><<<dim3(1536), dim3(256), 0, stream>>>(xb, Bf1, qkv_b, qkvo,
                                                   NM, 1536, 512, 12);
  natt<<<dim3(1024), dim3(256), 0, stream>>>(qkvo, rpb, attno);
  // out = attn @ proj_w + b  (fp32 out): 512 blocks
  gemm128<0><<<dim3(512), dim3(256), 0, stream>>>(attno, Bf2, proj_b, out,
                                                  NM, 512, 512, 4);
}

// Round 17
// 93.700 us; speedup vs baseline: 1.9747x; 1.0168x over previous
//
#include <hip/hip_runtime.h>
#include <hip/hip_bf16.h>
#include <stdint.h>

// NeighborhoodAttention1D: B=4, L=4096, C=512, H=16, hd=32, K=13
// cvt+pack (merged) ; GEMM1/GEMM2 (R8 structure, SINGLE barrier/K-tile) ; natt
// R16 = R14 stable baseline (93.6-95.3us). This round: remove BAR2 per tile
// (register-neutral reorder; see ledger below). Everything else untouched.

typedef __attribute__((ext_vector_type(8))) short short8;   // 8 x bf16 frag
typedef __attribute__((ext_vector_type(4))) float f32x4;    // MFMA C/D frag
typedef __attribute__((ext_vector_type(8))) unsigned short u16x8;
typedef __attribute__((ext_vector_type(4))) float float4v;

#define NB 4
#define NL 4096
#define NC 512
#define NH 16
#define HD 32
#define KW 13
#define KHALF 6
#define NM (NB*NL)   // 16384 rows

__device__ __forceinline__ float b2f(unsigned short u) {
  union { unsigned int i; float f; } x; x.i = ((unsigned int)u) << 16; return x.f;
}
__device__ __forceinline__ unsigned short f2b(float f) {
  __hip_bfloat16 h = __float2bfloat16(f);   // RNE
  return __builtin_bit_cast(unsigned short, h);
}
__device__ __forceinline__ void gll16(const void* g, unsigned short* l) {
  __builtin_amdgcn_global_load_lds(
      (const __attribute__((address_space(1))) void*)g,
      (__attribute__((address_space(3))) void*)l, 16, 0, 0);
}

// ---- merged: x->bf16 convert (blocks 0..4095) + W frag-pack (4096..4607) ---
// R8 pack grouping: g = ((((tn*8+kt)*2+wn)*4+nj)*2+kb)*64 + lane
//   n = tn*128 + wn*64 + nj*16 + (lane&15), k = kt*64 + (kb*4+(lane>>4))*8 + e
__device__ __forceinline__ void pack_one(const float* __restrict__ W,
                                         unsigned short* __restrict__ Bf,
                                         int N, int g) {
  int lane = g & 63;
  int kb   = (g >> 6) & 1;
  int nj   = (g >> 7) & 3;
  int wn   = (g >> 9) & 1;
  int kt   = (g >> 10) & 7;
  int tn   = g >> 13;
  int n  = tn * 128 + wn * 64 + nj * 16 + (lane & 15);
  int k0 = kt * 64 + (kb * 4 + (lane >> 4)) * 8;
  u16x8 u;
  #pragma unroll
  for (int e = 0; e < 8; ++e) u[e] = f2b(W[(long)(k0 + e) * N + n]);
  ((u16x8*)Bf)[g] = u;
}
__global__ __launch_bounds__(256)
void cvt_and_pack(const float* __restrict__ x, unsigned short* __restrict__ xb,
                  const float* __restrict__ W1, unsigned short* __restrict__ Bf1,
                  const float* __restrict__ W2, unsigned short* __restrict__ Bf2) {
  int bid = blockIdx.x;
  if (bid < 4096) {                      // x -> bf16, 8 elems/thread
    long i = (long)bid * 256 + threadIdx.x;
    const float4v* in4 = (const float4v*)x;
    float4v a = in4[i * 2];
    float4v b = in4[i * 2 + 1];
    u16x8 u;
    u[0] = f2b(a.x); u[1] = f2b(a.y); u[2] = f2b(a.z); u[3] = f2b(a.w);
    u[4] = f2b(b.x); u[5] = f2b(b.y); u[6] = f2b(b.z); u[7] = f2b(b.w);
    ((u16x8*)xb)[i] = u;
  } else {                               // weight packing (131072 groups)
    int g = (bid - 4096) * 256 + threadIdx.x;
    if (g < 98304) pack_one(W1, Bf1, 1536, g);
    else           pack_one(W2, Bf2, 512, g - 98304);
  }
}

#define BAR() __builtin_amdgcn_s_barrier()
#define LGK0() do { asm volatile("s_waitcnt lgkmcnt(0)" ::: "memory"); \
                    __builtin_amdgcn_sched_barrier(0); } while (0)
#define VM(N) asm volatile("s_waitcnt vmcnt(" #N ")" ::: "memory")

// ====== 128x128 GEMM: A-only LDS (32KB dbuf), B frag-direct, 1 BAR/tile ====
// C[M,N] = A[M,K]*W + bias, W frag-packed. K=512 -> 8 K-tiles of 64.
// 256 threads = 4 waves (2M x 2N), per-wave 64x64 out = acc[4][4].
// Regs: identical live set to R8/R14 (acc 64 + af 16 + bf 16 + addr ~110,
// VGPR 128 @ bounds(256,3)) -- the ONLY stable alloc point (R9/11/13/15).
// Per tile kt (buf kt&1):  LDBG(kt) | LDA(buf) | lgkm0 | VM(4) | BAR |
//   stage A(kt+2)->buf | MFMA        [single barrier -- was 2 in R14]
// Correctness ledger:
//  WAR (stage overwrites buf just read): every wave's ds_reads drained at its
//    own lgkm0 BEFORE the BAR; stage is program-after BAR. OK.
//  Publication of A(kt+1) (staged tile kt-1 post-BAR): wave issue order is
//    ... A(kt+1)4 [tile kt-1, post-BAR], B(kt)8 [tile kt head] -> at tile kt
//    VM(4) the 12 outstanding retire down to 4 = A(kt+1) fully landed (and 4
//    of B(kt)); every wave passes its VM(4) then BAR; tile kt+1's LDA is
//    program-after that BAR -> sees complete A(kt+1). MFMA's remaining B(kt)
//    waits are compiler-inserted register deps. OK.
//  Tails: kt=6 VM(4) retires A(7) (oldest) -> published for tile 7; kt=7 no
//    manual VM (compiler waits bf). No stage at kt>=6.
// Swizzle: chunk ^= (row&7), both-sides (R2..R8-verified: 0 bank conflicts).

__device__ __forceinline__ void stage_tileA(const unsigned short* __restrict__ G,
                                            long rowBase, int K, int kt,
                                            unsigned short* ldsDst, int tid) {
  int r  = tid >> 3;                       // 0..31
  int ch = (tid & 7) ^ (r & 7);            // inverse-swizzled source chunk
  const unsigned short* s0 = G + (rowBase + r) * (long)K + kt * 64 + ch * 8;
  unsigned short* d0 = ldsDst + tid * 8;
  #pragma unroll
  for (int q = 0; q < 4; ++q)              // rows r, r+32, r+64, r+96
    gll16(s0 + (long)32 * q * K, d0 + 2048 * q);
}

// af[ii][kb] <- A row wm*64 + ii*16 + lr, 16B chunk (kb*4+lk)^(row&7)
#define LDA_B16(ABASE) do { \
  const char* _ba = (const char*)(ABASE); \
  _Pragma("unroll") for (int ii = 0; ii < 4; ++ii) { \
    int _row = wm*64 + ii*16 + lr; \
    _Pragma("unroll") for (int kb = 0; kb < 2; ++kb) \
      af[ii][kb] = *(const short8*)(_ba + _row*128 + (((kb*4+lk) ^ lr7) * 16)); \
  } \
} while (0)

// bf[nj][kb] <- packed B frags for K-tile KT (8 coalesced 16B loads, L2-hot)
#define LDBG(KT) do { \
  const short8* _bp = (const short8*)(Bfw + (long)(KT) * 8192) + lane; \
  _Pragma("unroll") for (int nj = 0; nj < 4; ++nj) \
    _Pragma("unroll") for (int kb = 0; kb < 2; ++kb) \
      bf[nj][kb] = _bp[(nj*2 + kb) * 64]; \
} while (0)

#define MMA_ALL() do { \
  __builtin_amdgcn_s_setprio(1); \
  _Pragma("unroll") for (int ii = 0; ii < 4; ++ii) \
    _Pragma("unroll") for (int jj = 0; jj < 4; ++jj) \
      _Pragma("unroll") for (int kb = 0; kb < 2; ++kb) \
        acc[ii][jj] = __builtin_amdgcn_mfma_f32_16x16x32_bf16( \
            af[ii][kb], bf[jj][kb], acc[ii][jj], 0, 0, 0); \
  __builtin_amdgcn_s_setprio(0); \
} while (0)

#define GTILE(ABUF, KT, STG, VMARG) do { \
  LDBG(KT); \
  LDA_B16(ABUF); \
  LGK0(); \
  VMARG; \
  BAR(); \
  if (STG) stage_tileA(Ag, mBase, K, (KT) + 2, ABUF, tid); \
  MMA_ALL(); \
} while (0)

template<int OUT_BF16>
__global__ __launch_bounds__(256, 3)
void gemm128(const unsigned short* __restrict__ Ag,
             const unsigned short* __restrict__ Bf,
             const float* __restrict__ bias,
             void* __restrict__ Cout,
             int M, int N, int K, int tilesN) {
  __shared__ __align__(16) unsigned short lds[16384];   // 32 KiB (A dbuf)

  int tid = threadIdx.x;
  int nwg = gridDim.x;                   // 1536 / 512, both %8==0
  int cpx = nwg >> 3;
  int wg  = ((int)blockIdx.x & 7) * cpx + ((int)blockIdx.x >> 3);  // XCD swizzle
  int tm = wg / tilesN, tn = wg % tilesN;
  long mBase = (long)tm * 128;
  long nBase = (long)tn * 128;

  int lane = tid & 63, wave = tid >> 6;
  int wm = wave >> 1, wn = wave & 1;
  int lr = lane & 15, lk = lane >> 4, lr7 = lr & 7;

  const unsigned short* Bfw = Bf + (long)tn * 65536 + wn * 4096;

  unsigned short* A0 = lds;              // buf0 A (128x64 bf16)
  unsigned short* A1 = lds + 8192;       // buf1 A

  f32x4 acc[4][4];
  #pragma unroll
  for (int i = 0; i < 4; ++i)
    #pragma unroll
    for (int j = 0; j < 4; ++j) acc[i][j] = (f32x4){0.f, 0.f, 0.f, 0.f};

  short8 af[4][2], bf[4][2];

  // ---- prologue: A(0)->buf0, A(1)->buf1 (8 gll16/thread) ----
  stage_tileA(Ag, mBase, K, 0, A0, tid);
  stage_tileA(Ag, mBase, K, 1, A1, tid);
  VM(4);                       // A(0) landed (A(1)'s 4 in flight)
  BAR();

  #pragma unroll 1
  for (int i = 0; i < 3; ++i) {
    GTILE(A0, 2*i,     true, VM(4));
    GTILE(A1, 2*i + 1, true, VM(4));
  }
  GTILE(A0, 6, false, VM(4));          // retires A(7) (oldest outstanding)
  GTILE(A1, 7, false, (void)0);        // compiler waits bf

  // ---- epilogue: C/D layout col = lane&15, row = (lane>>4)*4 + r --------
  long rowb = mBase + wm * 64 + (lane >> 4) * 4;
  int  colb = (int)nBase + wn * 64 + lr;
  if (OUT_BF16) {
    unsigned short* C = (unsigned short*)Cout;
    #pragma unroll
    for (int mi = 0; mi < 4; ++mi)
      #pragma unroll
      for (int nj = 0; nj < 4; ++nj) {
        int col = colb + nj * 16;
        float bv = bias[col];
        #pragma unroll
        for (int r = 0; r < 4; ++r)
          C[(rowb + mi * 16 + r) * (long)N + col] = f2b(acc[mi][nj][r] + bv);
      }
  } else {
    float* C = (float*)Cout;
    #pragma unroll
    for (int mi = 0; mi < 4; ++mi)
      #pragma unroll
      for (int nj = 0; nj < 4; ++nj) {
        int col = colb + nj * 16;
        float bv = bias[col];
        #pragma unroll
        for (int r = 0; r < 4; ++r)
          C[(rowb + mi * 16 + r) * (long)N + col] = acc[mi][nj][r] + bv;
      }
  }
}

// ---------------- neighborhood attention: 1 thread per (b,l,h) ------------
__global__ __launch_bounds__(256)
void natt(const unsigned short* __restrict__ qkv, const float* __restrict__ rpb,
          unsigned short* __restrict__ out) {
  int tid = blockIdx.x * 256 + threadIdx.x;
  int h = tid & 15;
  int l = (tid >> 4) & (NL - 1);
  int b = tid >> 16;
  const float scale = 0.17677669529663687f;

  long qb = ((long)(b * NL + l) * 3) * NC + h * HD;
  float q[HD];
  {
    const u16x8* q8 = (const u16x8*)(qkv + qb);
    #pragma unroll
    for (int w = 0; w < 4; ++w) {
      u16x8 u = q8[w];
      #pragma unroll
      for (int e = 0; e < 8; ++e) q[w * 8 + e] = b2f(u[e]) * scale;
    }
  }

  int ni = l - KHALF;
  if (ni < 0) ni = 0;
  if (ni > NL - KW) ni = NL - KW;
  const float* rb = rpb + h * (2 * KW - 1) + (ni - l + KW - 1);

  float p[KW];
  float mx = -1e30f;
  #pragma unroll
  for (int j = 0; j < KW; ++j) {
    long kb = ((long)(b * NL + ni + j) * 3 + 1) * NC + h * HD;
    const u16x8* k8 = (const u16x8*)(qkv + kb);
    float s = 0.f;
    #pragma unroll
    for (int w = 0; w < 4; ++w) {
      u16x8 u = k8[w];
      #pragma unroll
      for (int e = 0; e < 8; ++e) s += q[w * 8 + e] * b2f(u[e]);
    }
    s += rb[j];
    p[j] = s;
    mx = fmaxf(mx, s);
  }

  float sum = 0.f;
  #pragma unroll
  for (int j = 0; j < KW; ++j) { p[j] = __expf(p[j] - mx); sum += p[j]; }
  float inv = 1.0f / sum;

  float o[HD];
  #pragma unroll
  for (int d = 0; d < HD; ++d) o[d] = 0.f;
  #pragma unroll
  for (int j = 0; j < KW; ++j) {
    long vb = ((long)(b * NL + ni + j) * 3 + 2) * NC + h * HD;
    const u16x8* v8 = (const u16x8*)(qkv + vb);
    float wj = p[j] * inv;
    #pragma unroll
    for (int w = 0; w < 4; ++w) {
      u16x8 u = v8[w];
      #pragma unroll
      for (int e = 0; e < 8; ++e) o[w * 8 + e] += wj * b2f(u[e]);
    }
  }

  unsigned short* op = out + (long)(b * NL + l) * NC + h * HD;
  #pragma unroll
  for (int w = 0; w < 4; ++w) {
    u16x8 u;
    #pragma unroll
    for (int e = 0; e < 8; ++e) u[e] = f2b(o[w * 8 + e]);
    *((u16x8*)(op + w * 8)) = u;
  }
}

// ---------------------------------------------------------------------------
extern "C" void kernel_launch(void* const* d_in, const int* in_sizes, int n_in,
                              void* d_out, int out_size, void* d_ws, size_t ws_size,
                              hipStream_t stream) {
  const float* x      = (const float*)d_in[0];
  const float* qkv_w  = (const float*)d_in[1];
  const float* qkv_b  = (const float*)d_in[2];
  const float* rpb    = (const float*)d_in[3];
  const float* proj_w = (const float*)d_in[4];
  const float* proj_b = (const float*)d_in[5];
  float* out = (float*)d_out;

  char* ws = (char*)d_ws;
  unsigned short* xb   = (unsigned short*)(ws);              // 16,777,216 B
  unsigned short* Bf1  = (unsigned short*)(ws + 16777216);   //  1,572,864 B
  unsigned short* Bf2  = (unsigned short*)(ws + 18350080);   //    524,288 B
  unsigned short* qkvo = (unsigned short*)(ws + 18874368);   // 50,331,648 B
  unsigned short* attno= (unsigned short*)(ws + 69206016);   // 16,777,216 B

  cvt_and_pack<<<dim3(4608), dim3(256), 0, stream>>>(x, xb, qkv_w, Bf1,
                                                     proj_w, Bf2);
  // qkv = x @ qkv_w + b   (bf16 out): 1536 blocks
  gemm128<1><<<dim3(1536), dim3(256), 0, stream>>>(xb, Bf1, qkv_b, qkvo,
                                                   NM, 1536, 512, 12);
  natt<<<dim3(1024), dim3(256), 0, stream>>>(qkvo, rpb, attno);
  // out = attn @ proj_w + b  (fp32 out): 512 blocks
  gemm128<0><<<dim3(512), dim3(256), 0, stream>>>(attno, Bf2, proj_b, out,
                                                  NM, 512, 512, 4);
}

// Round 18
// 92.674 us; speedup vs baseline: 1.9965x; 1.0111x over previous
//
#include <hip/hip_runtime.h>
#include <hip/hip_bf16.h>
#include <stdint.h>

// NeighborhoodAttention1D: B=4, L=4096, C=512, H=16, hd=32, K=13
// cvt+pack (merged) ; GEMM1/GEMM2 (R17 single-barrier structure, NO setprio) ;
// natt.  R18 change: drop s_setprio around MFMA — T5 is null-to-negative on
// lockstep GEMM (guide m190: −14TF@8k); it perturbs inter-block scheduling
// fairness that currently hides our per-tile stalls. Register-neutral.

typedef __attribute__((ext_vector_type(8))) short short8;   // 8 x bf16 frag
typedef __attribute__((ext_vector_type(4))) float f32x4;    // MFMA C/D frag
typedef __attribute__((ext_vector_type(8))) unsigned short u16x8;
typedef __attribute__((ext_vector_type(4))) float float4v;

#define NB 4
#define NL 4096
#define NC 512
#define NH 16
#define HD 32
#define KW 13
#define KHALF 6
#define NM (NB*NL)   // 16384 rows

__device__ __forceinline__ float b2f(unsigned short u) {
  union { unsigned int i; float f; } x; x.i = ((unsigned int)u) << 16; return x.f;
}
__device__ __forceinline__ unsigned short f2b(float f) {
  __hip_bfloat16 h = __float2bfloat16(f);   // RNE
  return __builtin_bit_cast(unsigned short, h);
}
__device__ __forceinline__ void gll16(const void* g, unsigned short* l) {
  __builtin_amdgcn_global_load_lds(
      (const __attribute__((address_space(1))) void*)g,
      (__attribute__((address_space(3))) void*)l, 16, 0, 0);
}

// ---- merged: x->bf16 convert (blocks 0..4095) + W frag-pack (4096..4607) ---
// R8 pack grouping: g = ((((tn*8+kt)*2+wn)*4+nj)*2+kb)*64 + lane
//   n = tn*128 + wn*64 + nj*16 + (lane&15), k = kt*64 + (kb*4+(lane>>4))*8 + e
__device__ __forceinline__ void pack_one(const float* __restrict__ W,
                                         unsigned short* __restrict__ Bf,
                                         int N, int g) {
  int lane = g & 63;
  int kb   = (g >> 6) & 1;
  int nj   = (g >> 7) & 3;
  int wn   = (g >> 9) & 1;
  int kt   = (g >> 10) & 7;
  int tn   = g >> 13;
  int n  = tn * 128 + wn * 64 + nj * 16 + (lane & 15);
  int k0 = kt * 64 + (kb * 4 + (lane >> 4)) * 8;
  u16x8 u;
  #pragma unroll
  for (int e = 0; e < 8; ++e) u[e] = f2b(W[(long)(k0 + e) * N + n]);
  ((u16x8*)Bf)[g] = u;
}
__global__ __launch_bounds__(256)
void cvt_and_pack(const float* __restrict__ x, unsigned short* __restrict__ xb,
                  const float* __restrict__ W1, unsigned short* __restrict__ Bf1,
                  const float* __restrict__ W2, unsigned short* __restrict__ Bf2) {
  int bid = blockIdx.x;
  if (bid < 4096) {                      // x -> bf16, 8 elems/thread
    long i = (long)bid * 256 + threadIdx.x;
    const float4v* in4 = (const float4v*)x;
    float4v a = in4[i * 2];
    float4v b = in4[i * 2 + 1];
    u16x8 u;
    u[0] = f2b(a.x); u[1] = f2b(a.y); u[2] = f2b(a.z); u[3] = f2b(a.w);
    u[4] = f2b(b.x); u[5] = f2b(b.y); u[6] = f2b(b.z); u[7] = f2b(b.w);
    ((u16x8*)xb)[i] = u;
  } else {                               // weight packing (131072 groups)
    int g = (bid - 4096) * 256 + threadIdx.x;
    if (g < 98304) pack_one(W1, Bf1, 1536, g);
    else           pack_one(W2, Bf2, 512, g - 98304);
  }
}

#define BAR() __builtin_amdgcn_s_barrier()
#define LGK0() do { asm volatile("s_waitcnt lgkmcnt(0)" ::: "memory"); \
                    __builtin_amdgcn_sched_barrier(0); } while (0)
#define VM(N) asm volatile("s_waitcnt vmcnt(" #N ")" ::: "memory")

// ====== 128x128 GEMM: A-only LDS (32KB dbuf), B frag-direct, 1 BAR/tile ====
// C[M,N] = A[M,K]*W + bias, W frag-packed. K=512 -> 8 K-tiles of 64.
// 256 threads = 4 waves (2M x 2N), per-wave 64x64 out = acc[4][4].
// Regs: acc 64 + af 16 + bf 16 + addr ~110 -> VGPR 128 @ bounds(256,3),
// the ONLY stable alloc point (R9/11/13/15 = 4 regalloc failure modes).
// Per tile kt (buf kt&1):  LDBG(kt) | LDA(buf) | lgkm0 | VM(4) | BAR |
//   stage A(kt+2)->buf | MFMA     [R17 single-barrier ledger, verified]
//  WAR: all waves' ds_reads drained at own lgkm0 before BAR; stage after.
//  Publication: VM(4) retires A(kt+1) pre-BAR in every wave; next LDA is
//    program-after BAR. Tails: kt=6 VM(4) retires A(7); kt=7 compiler waits.
// Swizzle: chunk ^= (row&7), both-sides (R2..R8-verified: 0 bank conflicts).

__device__ __forceinline__ void stage_tileA(const unsigned short* __restrict__ G,
                                            long rowBase, int K, int kt,
                                            unsigned short* ldsDst, int tid) {
  int r  = tid >> 3;                       // 0..31
  int ch = (tid & 7) ^ (r & 7);            // inverse-swizzled source chunk
  const unsigned short* s0 = G + (rowBase + r) * (long)K + kt * 64 + ch * 8;
  unsigned short* d0 = ldsDst + tid * 8;
  #pragma unroll
  for (int q = 0; q < 4; ++q)              // rows r, r+32, r+64, r+96
    gll16(s0 + (long)32 * q * K, d0 + 2048 * q);
}

// af[ii][kb] <- A row wm*64 + ii*16 + lr, 16B chunk (kb*4+lk)^(row&7)
#define LDA_B16(ABASE) do { \
  const char* _ba = (const char*)(ABASE); \
  _Pragma("unroll") for (int ii = 0; ii < 4; ++ii) { \
    int _row = wm*64 + ii*16 + lr; \
    _Pragma("unroll") for (int kb = 0; kb < 2; ++kb) \
      af[ii][kb] = *(const short8*)(_ba + _row*128 + (((kb*4+lk) ^ lr7) * 16)); \
  } \
} while (0)

// bf[nj][kb] <- packed B frags for K-tile KT (8 coalesced 16B loads, L2-hot)
#define LDBG(KT) do { \
  const short8* _bp = (const short8*)(Bfw + (long)(KT) * 8192) + lane; \
  _Pragma("unroll") for (int nj = 0; nj < 4; ++nj) \
    _Pragma("unroll") for (int kb = 0; kb < 2; ++kb) \
      bf[nj][kb] = _bp[(nj*2 + kb) * 64]; \
} while (0)

#define MMA_ALL() do { \
  _Pragma("unroll") for (int ii = 0; ii < 4; ++ii) \
    _Pragma("unroll") for (int jj = 0; jj < 4; ++jj) \
      _Pragma("unroll") for (int kb = 0; kb < 2; ++kb) \
        acc[ii][jj] = __builtin_amdgcn_mfma_f32_16x16x32_bf16( \
            af[ii][kb], bf[jj][kb], acc[ii][jj], 0, 0, 0); \
} while (0)

#define GTILE(ABUF, KT, STG, VMARG) do { \
  LDBG(KT); \
  LDA_B16(ABUF); \
  LGK0(); \
  VMARG; \
  BAR(); \
  if (STG) stage_tileA(Ag, mBase, K, (KT) + 2, ABUF, tid); \
  MMA_ALL(); \
} while (0)

template<int OUT_BF16>
__global__ __launch_bounds__(256, 3)
void gemm128(const unsigned short* __restrict__ Ag,
             const unsigned short* __restrict__ Bf,
             const float* __restrict__ bias,
             void* __restrict__ Cout,
             int M, int N, int K, int tilesN) {
  __shared__ __align__(16) unsigned short lds[16384];   // 32 KiB (A dbuf)

  int tid = threadIdx.x;
  int nwg = gridDim.x;                   // 1536 / 512, both %8==0
  int cpx = nwg >> 3;
  int wg  = ((int)blockIdx.x & 7) * cpx + ((int)blockIdx.x >> 3);  // XCD swizzle
  int tm = wg / tilesN, tn = wg % tilesN;
  long mBase = (long)tm * 128;
  long nBase = (long)tn * 128;

  int lane = tid & 63, wave = tid >> 6;
  int wm = wave >> 1, wn = wave & 1;
  int lr = lane & 15, lk = lane >> 4, lr7 = lr & 7;

  const unsigned short* Bfw = Bf + (long)tn * 65536 + wn * 4096;

  unsigned short* A0 = lds;              // buf0 A (128x64 bf16)
  unsigned short* A1 = lds + 8192;       // buf1 A

  f32x4 acc[4][4];
  #pragma unroll
  for (int i = 0; i < 4; ++i)
    #pragma unroll
    for (int j = 0; j < 4; ++j) acc[i][j] = (f32x4){0.f, 0.f, 0.f, 0.f};

  short8 af[4][2], bf[4][2];

  // ---- prologue: A(0)->buf0, A(1)->buf1 (8 gll16/thread) ----
  stage_tileA(Ag, mBase, K, 0, A0, tid);
  stage_tileA(Ag, mBase, K, 1, A1, tid);
  VM(4);                       // A(0) landed (A(1)'s 4 in flight)
  BAR();

  #pragma unroll 1
  for (int i = 0; i < 3; ++i) {
    GTILE(A0, 2*i,     true, VM(4));
    GTILE(A1, 2*i + 1, true, VM(4));
  }
  GTILE(A0, 6, false, VM(4));          // retires A(7) (oldest outstanding)
  GTILE(A1, 7, false, (void)0);        // compiler waits bf

  // ---- epilogue: C/D layout col = lane&15, row = (lane>>4)*4 + r --------
  long rowb = mBase + wm * 64 + (lane >> 4) * 4;
  int  colb = (int)nBase + wn * 64 + lr;
  if (OUT_BF16) {
    unsigned short* C = (unsigned short*)Cout;
    #pragma unroll
    for (int mi = 0; mi < 4; ++mi)
      #pragma unroll
      for (int nj = 0; nj < 4; ++nj) {
        int col = colb + nj * 16;
        float bv = bias[col];
        #pragma unroll
        for (int r = 0; r < 4; ++r)
          C[(rowb + mi * 16 + r) * (long)N + col] = f2b(acc[mi][nj][r] + bv);
      }
  } else {
    float* C = (float*)Cout;
    #pragma unroll
    for (int mi = 0; mi < 4; ++mi)
      #pragma unroll
      for (int nj = 0; nj < 4; ++nj) {
        int col = colb + nj * 16;
        float bv = bias[col];
        #pragma unroll
        for (int r = 0; r < 4; ++r)
          C[(rowb + mi * 16 + r) * (long)N + col] = acc[mi][nj][r] + bv;
      }
  }
}

// ---------------- neighborhood attention: 1 thread per (b,l,h) ------------
__global__ __launch_bounds__(256)
void natt(const unsigned short* __restrict__ qkv, const float* __restrict__ rpb,
          unsigned short* __restrict__ out) {
  int tid = blockIdx.x * 256 + threadIdx.x;
  int h = tid & 15;
  int l = (tid >> 4) & (NL - 1);
  int b = tid >> 16;
  const float scale = 0.17677669529663687f;

  long qb = ((long)(b * NL + l) * 3) * NC + h * HD;
  float q[HD];
  {
    const u16x8* q8 = (const u16x8*)(qkv + qb);
    #pragma unroll
    for (int w = 0; w < 4; ++w) {
      u16x8 u = q8[w];
      #pragma unroll
      for (int e = 0; e < 8; ++e) q[w * 8 + e] = b2f(u[e]) * scale;
    }
  }

  int ni = l - KHALF;
  if (ni < 0) ni = 0;
  if (ni > NL - KW) ni = NL - KW;
  const float* rb = rpb + h * (2 * KW - 1) + (ni - l + KW - 1);

  float p[KW];
  float mx = -1e30f;
  #pragma unroll
  for (int j = 0; j < KW; ++j) {
    long kb = ((long)(b * NL + ni + j) * 3 + 1) * NC + h * HD;
    const u16x8* k8 = (const u16x8*)(qkv + kb);
    float s = 0.f;
    #pragma unroll
    for (int w = 0; w < 4; ++w) {
      u16x8 u = k8[w];
      #pragma unroll
      for (int e = 0; e < 8; ++e) s += q[w * 8 + e] * b2f(u[e]);
    }
    s += rb[j];
    p[j] = s;
    mx = fmaxf(mx, s);
  }

  float sum = 0.f;
  #pragma unroll
  for (int j = 0; j < KW; ++j) { p[j] = __expf(p[j] - mx); sum += p[j]; }
  float inv = 1.0f / sum;

  float o[HD];
  #pragma unroll
  for (int d = 0; d < HD; ++d) o[d] = 0.f;
  #pragma unroll
  for (int j = 0; j < KW; ++j) {
    long vb = ((long)(b * NL + ni + j) * 3 + 2) * NC + h * HD;
    const u16x8* v8 = (const u16x8*)(qkv + vb);
    float wj = p[j] * inv;
    #pragma unroll
    for (int w = 0; w < 4; ++w) {
      u16x8 u = v8[w];
      #pragma unroll
      for (int e = 0; e < 8; ++e) o[w * 8 + e] += wj * b2f(u[e]);
    }
  }

  unsigned short* op = out + (long)(b * NL + l) * NC + h * HD;
  #pragma unroll
  for (int w = 0; w < 4; ++w) {
    u16x8 u;
    #pragma unroll
    for (int e = 0; e < 8; ++e) u[e] = f2b(o[w * 8 + e]);
    *((u16x8*)(op + w * 8)) = u;
  }
}

// ---------------------------------------------------------------------------
extern "C" void kernel_launch(void* const* d_in, const int* in_sizes, int n_in,
                              void* d_out, int out_size, void* d_ws, size_t ws_size,
                              hipStream_t stream) {
  const float* x      = (const float*)d_in[0];
  const float* qkv_w  = (const float*)d_in[1];
  const float* qkv_b  = (const float*)d_in[2];
  const float* rpb    = (const float*)d_in[3];
  const float* proj_w = (const float*)d_in[4];
  const float* proj_b = (const float*)d_in[5];
  float* out = (float*)d_out;

  char* ws = (char*)d_ws;
  unsigned short* xb   = (unsigned short*)(ws);              // 16,777,216 B
  unsigned short* Bf1  = (unsigned short*)(ws + 16777216);   //  1,572,864 B
  unsigned short* Bf2  = (unsigned short*)(ws + 18350080);   //    524,288 B
  unsigned short* qkvo = (unsigned short*)(ws + 18874368);   // 50,331,648 B
  unsigned short* attno= (unsigned short*)(ws + 69206016);   // 16,777,216 B

  cvt_and_pack<<<dim3(4608), dim3(256), 0, stream>>>(x, xb, qkv_w, Bf1,
                                                     proj_w, Bf2);
  // qkv = x @ qkv_w + b   (bf16 out): 1536 blocks
  gemm128<1><<<dim3(1536), dim3(256), 0, stream>>>(xb, Bf1, qkv_b, qkvo,
                                                   NM, 1536, 512, 12);
  natt<<<dim3(1024), dim3(256), 0, stream>>>(qkvo, rpb, attno);
  // out = attn @ proj_w + b  (fp32 out): 512 blocks
  gemm128<0><<<dim3(512), dim3(256), 0, stream>>>(attno, Bf2, proj_b, out,
                                                  NM, 512, 512, 4);
}